// Round 3
// baseline (833.444 us; speedup 1.0000x reference)
//
#include <hip/hip_runtime.h>

#define H 2048
#define W 2048
#define KS 97     // int(2*(4*12+0.5)) = 97, odd
#define KH 48
#define KP 104    // taps zero-padded (mult of 8): g[97..103]=0
#define TR 32     // output rows per thread, vertical pass

// ---------------------------------------------------------------------------
// wts layout: [0..103]=g0 (sigma0, zero-padded), [104..207]=g1, [208]=a0, [209]=a1
// ---------------------------------------------------------------------------
__global__ __launch_bounds__(128) void make_weights_k(const float* __restrict__ log_sigma,
                                                      const float* __restrict__ log_alpha,
                                                      float* __restrict__ wts) {
    __shared__ float e0s[KS], e1s[KS];
    __shared__ float sums[2];
    const int t = threadIdx.x;
    const float s0 = expf(log_sigma[0]);
    const float s1 = expf(log_sigma[1]);
    if (t < KS) {
        const float xx = (float)(t - KH);
        e0s[t] = expf(-(xx * xx) / (2.f * s0 * s0));
        e1s[t] = expf(-(xx * xx) / (2.f * s1 * s1));
    }
    __syncthreads();
    if (t == 0) {
        float a = 0.f, b = 0.f;
        for (int k = 0; k < KS; ++k) { a += e0s[k]; b += e1s[k]; }
        sums[0] = a; sums[1] = b;
    }
    __syncthreads();
    if (t < KP) {
        wts[t]      = (t < KS) ? e0s[t] / sums[0] : 0.f;
        wts[KP + t] = (t < KS) ? e1s[t] / sums[1] : 0.f;
    }
    if (t == 0) {
        wts[2 * KP]     = expf(log_alpha[0]);
        wts[2 * KP + 1] = expf(log_alpha[1]);
    }
}

// ---------------------------------------------------------------------------
// Kernel 1: vertical 97-tap blur of (d_rand*2-1), zero-padded SAME.
// 32 output rows per thread, 2 cols (float2), 32-deep register ring window.
// Row r lives in ring slot (r-base)&31. Halo amp = 135/32 = 4.2x.
// No LDS: taps come from uniform s_loads (lgkmcnt has no LDS interference).
// ---------------------------------------------------------------------------
template <bool GUARD>
__device__ __forceinline__ float2 vload_row(const float* __restrict__ src, int row, int col) {
    float2 v = make_float2(0.f, 0.f);
    if (!GUARD || ((unsigned)row < (unsigned)H)) {
        const float2 r2 = *(const float2*)(src + (size_t)row * W + col);
        v.x = fmaf(r2.x, 2.f, -1.f);
        v.y = fmaf(r2.y, 2.f, -1.f);
    }
    return v;
}

template <bool GUARD>
__device__ __forceinline__ void vblur_body(const float* __restrict__ src,
                                           const float* __restrict__ g,
                                           float* __restrict__ dst,
                                           int col, int i0) {
    const int base = i0 - KH;
    float2 win[32];
    float2 acc[TR];
#pragma unroll
    for (int t = 0; t < TR; ++t) acc[t] = make_float2(0.f, 0.f);
#pragma unroll
    for (int t = 0; t < 31; ++t) win[t] = vload_row<GUARD>(src, base + t, col);

#pragma unroll 8
    for (int k = 0; k < KP; ++k) {
        win[(k + 31) & 31] = vload_row<GUARD>(src, base + k + 31, col);
        const float gk = g[k];   // uniform -> s_load; 0 for k>=97
#pragma unroll
        for (int t = 0; t < TR; ++t) {
            const float2 u = win[(k + t) & 31];
            acc[t].x = fmaf(gk, u.x, acc[t].x);
            acc[t].y = fmaf(gk, u.y, acc[t].y);
        }
    }
#pragma unroll
    for (int t = 0; t < TR; ++t)
        *(float2*)(dst + (size_t)(i0 + t) * W + col) = acc[t];
}

__global__ __launch_bounds__(256) void vblur_k(const float* __restrict__ drand,
                                               const float* __restrict__ wts,
                                               float* __restrict__ tmp) {
    const int c   = blockIdx.z;
    const int col = (blockIdx.x * 256 + threadIdx.x) * 2;
    const int i0  = blockIdx.y * TR;
    const float* __restrict__ src = drand + (size_t)c * H * W;
    const float* __restrict__ g   = wts + c * KP;
    float* __restrict__ dst       = tmp + (size_t)c * H * W;

    // rows touched: [i0-48, i0+86]; interior iff i0>=48 && i0+86<=2047
    if (i0 >= KH && i0 + 86 <= H - 1)
        vblur_body<false>(src, g, dst, col, i0);
    else
        vblur_body<true>(src, g, dst, col, i0);
}

// ---------------------------------------------------------------------------
// Kernel 2: horizontal 97-tap blur of tmp -> (dy,dx), scale by alpha, build
// sample coords, bilinear-gather image(3ch)+mask(1ch). 4 cols per thread;
// window and taps both via ds_read_b128 (2+2 per 4-tap group).
// Reference quirk: x-coordinate += dy (channel 0), y-coordinate += dx.
// ---------------------------------------------------------------------------
#define BC 1024                 // cols per block (256 thr x 4)
#define SW 1136                 // LDS row span (need idx <= 1131, 16B mult)
__global__ __launch_bounds__(256) void hblur_sample_k(const float* __restrict__ tmp,
                                                      const float* __restrict__ wts,
                                                      const float* __restrict__ image,
                                                      const float* __restrict__ mask,
                                                      float* __restrict__ out) {
    const int i   = blockIdx.y;
    const int j0  = blockIdx.x * BC;
    const int tid = threadIdx.x;

    __shared__ __align__(16) float s0[SW];
    __shared__ __align__(16) float s1[SW];
    __shared__ __align__(16) float g0s[KP];
    __shared__ __align__(16) float g1s[KP];

    if (tid < KP) { g0s[tid] = wts[tid]; g1s[tid] = wts[KP + tid]; }

    const float* __restrict__ t0 = tmp + (size_t)i * W;
    const float* __restrict__ t1 = tmp + (size_t)H * W + (size_t)i * W;
    for (int idx = tid; idx < SW / 4; idx += 256) {
        const int colb = j0 - KH + idx * 4;   // mult of 4 -> 16B aligned, all-in or all-out
        float4 v0 = make_float4(0.f, 0.f, 0.f, 0.f);
        float4 v1 = v0;
        if (colb >= 0 && colb + 3 < W) {
            v0 = *(const float4*)(t0 + colb);
            v1 = *(const float4*)(t1 + colb);
        }
        *(float4*)(s0 + idx * 4) = v0;
        *(float4*)(s1 + idx * 4) = v1;
    }
    __syncthreads();

    const int lb = tid * 4;

    float4 A0 = *(const float4*)(s0 + lb), B0 = *(const float4*)(s0 + lb + 4);
    float4 A1 = *(const float4*)(s1 + lb), B1 = *(const float4*)(s1 + lb + 4);
    float dy[4] = {0.f, 0.f, 0.f, 0.f}, dx[4] = {0.f, 0.f, 0.f, 0.f};

#pragma unroll
    for (int kg = 0; kg < KP / 4; ++kg) {     // 26 groups of 4 taps
        const int k0 = kg * 4;
        const float4 g0q = *(const float4*)(g0s + k0);   // broadcast
        const float4 g1q = *(const float4*)(g1s + k0);
        const float4 N0  = *(const float4*)(s0 + lb + k0 + 8);  // next window half
        const float4 N1  = *(const float4*)(s1 + lb + k0 + 8);  // (max idx 1131 < SW)
        const float e0[8] = {A0.x, A0.y, A0.z, A0.w, B0.x, B0.y, B0.z, B0.w};
        const float e1[8] = {A1.x, A1.y, A1.z, A1.w, B1.x, B1.y, B1.z, B1.w};
#pragma unroll
        for (int j = 0; j < 4; ++j) {
            const float gj0 = j == 0 ? g0q.x : j == 1 ? g0q.y : j == 2 ? g0q.z : g0q.w;
            const float gj1 = j == 0 ? g1q.x : j == 1 ? g1q.y : j == 2 ? g1q.z : g1q.w;
#pragma unroll
            for (int c = 0; c < 4; ++c) {
                dy[c] = fmaf(gj0, e0[c + j], dy[c]);
                dx[c] = fmaf(gj1, e1[c + j], dx[c]);
            }
        }
        A0 = B0; B0 = N0; A1 = B1; B1 = N1;
    }

    const float a0 = wts[2 * KP];
    const float a1 = wts[2 * KP + 1];
    const float step = 2.f / 2047.f;
    float res[4][4];
#pragma unroll
    for (int c = 0; c < 4; ++c) {
        const int j = j0 + lb + c;
        const float dyc = dy[c] * a0;
        const float dxc = dx[c] * a1;
        float xn = -1.f + (float)j * step + dyc;   // gx + dy  (reference quirk)
        float yn = -1.f + (float)i * step + dxc;   // gy + dx
        xn = fminf(fmaxf(xn, -1.f), 1.f);
        yn = fminf(fmaxf(yn, -1.f), 1.f);

        const float x = (xn + 1.f) * 0.5f * (float)(W - 1);
        const float y = (yn + 1.f) * 0.5f * (float)(H - 1);
        const float x0f = floorf(x), y0f = floorf(y);
        const float wx = x - x0f, wy = y - y0f;

        int x0 = (int)x0f, y0 = (int)y0f;
        int x1 = x0 + 1, y1 = y0 + 1;
        x0 = min(max(x0, 0), W - 1); x1 = min(max(x1, 0), W - 1);
        y0 = min(max(y0, 0), H - 1); y1 = min(max(y1, 0), H - 1);

        const float w00 = (1.f - wx) * (1.f - wy);
        const float w10 = wx * (1.f - wy);
        const float w01 = (1.f - wx) * wy;
        const float w11 = wx * wy;

        const size_t i00 = (size_t)y0 * W + x0;
        const size_t i10 = (size_t)y0 * W + x1;
        const size_t i01 = (size_t)y1 * W + x0;
        const size_t i11 = (size_t)y1 * W + x1;

#pragma unroll
        for (int p = 0; p < 3; ++p) {
            const float* __restrict__ pl = image + (size_t)p * H * W;
            res[p][c] = pl[i00] * w00 + pl[i10] * w10 + pl[i01] * w01 + pl[i11] * w11;
        }
        res[3][c] = mask[i00] * w00 + mask[i10] * w10 + mask[i01] * w01 + mask[i11] * w11;
    }

    const size_t o = (size_t)i * W + j0 + lb;
#pragma unroll
    for (int p = 0; p < 4; ++p)
        *(float4*)(out + (size_t)p * H * W + o) =
            make_float4(res[p][0], res[p][1], res[p][2], res[p][3]);
}

// ---------------------------------------------------------------------------
extern "C" void kernel_launch(void* const* d_in, const int* in_sizes, int n_in,
                              void* d_out, int out_size, void* d_ws, size_t ws_size,
                              hipStream_t stream) {
    const float* image     = (const float*)d_in[0];  // (3,2048,2048)
    const float* mask      = (const float*)d_in[1];  // (1,2048,2048)
    const float* drand     = (const float*)d_in[2];  // (1,2,2048,2048)
    const float* log_sigma = (const float*)d_in[3];  // (2,)
    const float* log_alpha = (const float*)d_in[4];  // (2,)
    float* out = (float*)d_out;                      // 3*HW img ++ 1*HW mask

    float* tmp = (float*)d_ws;                       // 2*H*W floats (32 MB)
    float* wts = tmp + (size_t)2 * H * W;            // 210 floats

    make_weights_k<<<1, 128, 0, stream>>>(log_sigma, log_alpha, wts);
    vblur_k<<<dim3(W / 512, H / TR, 2), 256, 0, stream>>>(drand, wts, tmp);
    hblur_sample_k<<<dim3(W / BC, H), 256, 0, stream>>>(tmp, wts, image, mask, out);
}

// Round 4
// 265.909 us; speedup vs baseline: 3.1343x; 3.1343x over previous
//
#include <hip/hip_runtime.h>

#define H 2048
#define W 2048
#define KS 97      // int(2*(4*12+0.5)) = 97, odd
#define KH 48
#define KPAD 112   // taps zero-padded to multiple of 16; g[97..111] = 0
#define TR 16      // output rows per thread, vertical pass (== ring depth == unroll)

// ---------------------------------------------------------------------------
// wts layout: [0..111]=g0 (sigma0, zero-padded), [112..223]=g1, [224]=a0, [225]=a1
// ---------------------------------------------------------------------------
__global__ __launch_bounds__(128) void make_weights_k(const float* __restrict__ log_sigma,
                                                      const float* __restrict__ log_alpha,
                                                      float* __restrict__ wts) {
    __shared__ float e0s[KS], e1s[KS];
    __shared__ float sums[2];
    const int t = threadIdx.x;
    const float s0 = expf(log_sigma[0]);
    const float s1 = expf(log_sigma[1]);
    if (t < KS) {
        const float xx = (float)(t - KH);
        e0s[t] = expf(-(xx * xx) / (2.f * s0 * s0));
        e1s[t] = expf(-(xx * xx) / (2.f * s1 * s1));
    }
    __syncthreads();
    if (t == 0) {
        float a = 0.f, b = 0.f;
        for (int k = 0; k < KS; ++k) { a += e0s[k]; b += e1s[k]; }
        sums[0] = a; sums[1] = b;
    }
    __syncthreads();
    if (t < KPAD) {
        wts[t]        = (t < KS) ? e0s[t] / sums[0] : 0.f;
        wts[KPAD + t] = (t < KS) ? e1s[t] / sums[1] : 0.f;
    }
    if (t == 0) {
        wts[2 * KPAD]     = expf(log_alpha[0]);
        wts[2 * KPAD + 1] = expf(log_alpha[1]);
    }
}

// ---------------------------------------------------------------------------
// Pack kernel: interleave image(3 planes)+mask into float4 so each bilinear
// corner in the sampler is ONE global_load_dwordx4 instead of 4 dword loads.
// ---------------------------------------------------------------------------
__global__ __launch_bounds__(256) void pack_k(const float* __restrict__ image,
                                              const float* __restrict__ mask,
                                              float4* __restrict__ packed) {
    const size_t HW = (size_t)H * W;
    const size_t idx = (size_t)blockIdx.x * 256 + threadIdx.x;
    packed[idx] = make_float4(image[idx], image[HW + idx], image[2 * HW + idx], mask[idx]);
}

// ---------------------------------------------------------------------------
// Kernel 1: vertical 97-tap blur of (d_rand*2-1), zero-padded SAME.
// 16 output rows/thread, 2 cols (float2), 16-deep register ring.
// CRITICAL: inner loop fully unrolled over r=0..15 so (r+t)&15 is a
// compile-time constant -> registers, never scratch (R3's spill bug).
// ---------------------------------------------------------------------------
template <bool GUARD>
__device__ __forceinline__ float2 vload_row(const float* __restrict__ src, int row, int col) {
    float2 v = make_float2(0.f, 0.f);
    if (!GUARD || ((unsigned)row < (unsigned)H)) {
        const float2 r2 = *(const float2*)(src + (size_t)row * W + col);
        v.x = fmaf(r2.x, 2.f, -1.f);
        v.y = fmaf(r2.y, 2.f, -1.f);
    }
    return v;
}

template <bool GUARD>
__device__ __forceinline__ void vblur_body(const float* __restrict__ src,
                                           const float* __restrict__ g,
                                           float* __restrict__ dst,
                                           int col, int i0) {
    const int base = i0 - KH;
    float2 win[16];
    float2 acc[TR];
#pragma unroll
    for (int t = 0; t < TR; ++t) acc[t] = make_float2(0.f, 0.f);
    // preload rows base+0..base+14 into slots 0..14
#pragma unroll
    for (int t = 0; t < 15; ++t) win[t] = vload_row<GUARD>(src, base + t, col);

    for (int m = 0; m < KPAD / 16; ++m) {       // 7 groups, dynamic loop
        const int kb = m * 16;
#pragma unroll
        for (int r = 0; r < 16; ++r) {          // fully unrolled: static ring idx
            const int k = kb + r;
            win[(r + 15) & 15] = vload_row<GUARD>(src, base + k + 15, col);
            const float gk = g[k];              // uniform -> s_load; 0 for k>=97
#pragma unroll
            for (int t = 0; t < TR; ++t) {
                const float2 u = win[(r + t) & 15];
                acc[t].x = fmaf(gk, u.x, acc[t].x);
                acc[t].y = fmaf(gk, u.y, acc[t].y);
            }
        }
    }
#pragma unroll
    for (int t = 0; t < TR; ++t)
        *(float2*)(dst + (size_t)(i0 + t) * W + col) = acc[t];
}

__global__ __launch_bounds__(256, 4) void vblur_k(const float* __restrict__ drand,
                                                  const float* __restrict__ wts,
                                                  float* __restrict__ tmp) {
    const int c   = blockIdx.z;
    const int col = (blockIdx.x * 256 + threadIdx.x) * 2;
    const int i0  = blockIdx.y * TR;
    const float* __restrict__ src = drand + (size_t)c * H * W;
    const float* __restrict__ g   = wts + c * KPAD;
    float* __restrict__ dst       = tmp + (size_t)c * H * W;

    // rows touched: [i0-48, i0+78]; interior iff i0>=48 && i0+78<=2047
    if (i0 >= KH && i0 + (KPAD - 1 + 15 - KH) <= H - 1)
        vblur_body<false>(src, g, dst, col, i0);
    else
        vblur_body<true>(src, g, dst, col, i0);
}

// ---------------------------------------------------------------------------
// Kernel 2: one block per row (512 thr x 4 px). Horizontal 97-tap blur of
// tmp -> (dy,dx), scale by alpha, bilinear gather, write 4 planes.
// PACKED: corners via one dwordx4 from interleaved buffer.
// Reference quirk: x-coordinate += dy (channel 0), y-coordinate += dx.
// ---------------------------------------------------------------------------
#define SW 2160     // LDS span: need idx <= 2155; mult of 4
template <bool PACKED>
__global__ __launch_bounds__(512) void hblur_sample_k(const float* __restrict__ tmp,
                                                      const float* __restrict__ wts,
                                                      const float* __restrict__ image,
                                                      const float* __restrict__ mask,
                                                      const float4* __restrict__ packed,
                                                      float* __restrict__ out) {
    const int i   = blockIdx.x;     // row
    const int tid = threadIdx.x;

    __shared__ __align__(16) float s0[SW];
    __shared__ __align__(16) float s1[SW];
    __shared__ __align__(16) float g0s[KPAD];
    __shared__ __align__(16) float g1s[KPAD];

    if (tid < KPAD) { g0s[tid] = wts[tid]; g1s[tid] = wts[KPAD + tid]; }

    const float* __restrict__ t0 = tmp + (size_t)i * W;
    const float* __restrict__ t1 = tmp + (size_t)H * W + (size_t)i * W;
    for (int idx = tid; idx < SW / 4; idx += 512) {
        const int colb = idx * 4 - KH;        // 16B aligned; all-in or all-out
        float4 v0 = make_float4(0.f, 0.f, 0.f, 0.f);
        float4 v1 = v0;
        if (colb >= 0 && colb + 3 < W) {
            v0 = *(const float4*)(t0 + colb);
            v1 = *(const float4*)(t1 + colb);
        }
        *(float4*)(s0 + idx * 4) = v0;
        *(float4*)(s1 + idx * 4) = v1;
    }
    __syncthreads();

    const int lb = tid * 4;                   // first of 4 pixels

    float4 A0 = *(const float4*)(s0 + lb), B0 = *(const float4*)(s0 + lb + 4);
    float4 A1 = *(const float4*)(s1 + lb), B1 = *(const float4*)(s1 + lb + 4);
    float dy[4] = {0.f, 0.f, 0.f, 0.f}, dx[4] = {0.f, 0.f, 0.f, 0.f};

#pragma unroll
    for (int kg = 0; kg < 26; ++kg) {         // 26 groups of 4 taps (g[97..103]=0)
        const int k0 = kg * 4;
        const float4 g0q = *(const float4*)(g0s + k0);       // broadcast
        const float4 g1q = *(const float4*)(g1s + k0);
        const float4 N0  = *(const float4*)(s0 + lb + k0 + 8);
        const float4 N1  = *(const float4*)(s1 + lb + k0 + 8);
        const float e0[8] = {A0.x, A0.y, A0.z, A0.w, B0.x, B0.y, B0.z, B0.w};
        const float e1[8] = {A1.x, A1.y, A1.z, A1.w, B1.x, B1.y, B1.z, B1.w};
#pragma unroll
        for (int j = 0; j < 4; ++j) {
            const float gj0 = j == 0 ? g0q.x : j == 1 ? g0q.y : j == 2 ? g0q.z : g0q.w;
            const float gj1 = j == 0 ? g1q.x : j == 1 ? g1q.y : j == 2 ? g1q.z : g1q.w;
#pragma unroll
            for (int c = 0; c < 4; ++c) {
                dy[c] = fmaf(gj0, e0[c + j], dy[c]);
                dx[c] = fmaf(gj1, e1[c + j], dx[c]);
            }
        }
        A0 = B0; B0 = N0; A1 = B1; B1 = N1;
    }

    const float a0 = wts[2 * KPAD];
    const float a1 = wts[2 * KPAD + 1];
    const float step = 2.f / 2047.f;
    float res[4][4];
#pragma unroll
    for (int c = 0; c < 4; ++c) {
        const int j = lb + c;
        const float dyc = dy[c] * a0;
        const float dxc = dx[c] * a1;
        float xn = -1.f + (float)j * step + dyc;   // gx + dy  (reference quirk)
        float yn = -1.f + (float)i * step + dxc;   // gy + dx
        xn = fminf(fmaxf(xn, -1.f), 1.f);
        yn = fminf(fmaxf(yn, -1.f), 1.f);

        const float x = (xn + 1.f) * 0.5f * (float)(W - 1);
        const float y = (yn + 1.f) * 0.5f * (float)(H - 1);
        const float x0f = floorf(x), y0f = floorf(y);
        const float wx = x - x0f, wy = y - y0f;

        int x0 = (int)x0f, y0 = (int)y0f;
        int x1 = x0 + 1, y1 = y0 + 1;
        x0 = min(max(x0, 0), W - 1); x1 = min(max(x1, 0), W - 1);
        y0 = min(max(y0, 0), H - 1); y1 = min(max(y1, 0), H - 1);

        const float w00 = (1.f - wx) * (1.f - wy);
        const float w10 = wx * (1.f - wy);
        const float w01 = (1.f - wx) * wy;
        const float w11 = wx * wy;

        const size_t i00 = (size_t)y0 * W + x0;
        const size_t i10 = (size_t)y0 * W + x1;
        const size_t i01 = (size_t)y1 * W + x0;
        const size_t i11 = (size_t)y1 * W + x1;

        if (PACKED) {
            const float4 v00 = packed[i00], v10 = packed[i10];
            const float4 v01 = packed[i01], v11 = packed[i11];
            res[0][c] = v00.x * w00 + v10.x * w10 + v01.x * w01 + v11.x * w11;
            res[1][c] = v00.y * w00 + v10.y * w10 + v01.y * w01 + v11.y * w11;
            res[2][c] = v00.z * w00 + v10.z * w10 + v01.z * w01 + v11.z * w11;
            res[3][c] = v00.w * w00 + v10.w * w10 + v01.w * w01 + v11.w * w11;
        } else {
#pragma unroll
            for (int p = 0; p < 3; ++p) {
                const float* __restrict__ pl = image + (size_t)p * H * W;
                res[p][c] = pl[i00] * w00 + pl[i10] * w10 + pl[i01] * w01 + pl[i11] * w11;
            }
            res[3][c] = mask[i00] * w00 + mask[i10] * w10 + mask[i01] * w01 + mask[i11] * w11;
        }
    }

    const size_t o = (size_t)i * W + lb;
#pragma unroll
    for (int p = 0; p < 4; ++p)
        *(float4*)(out + (size_t)p * H * W + o) =
            make_float4(res[p][0], res[p][1], res[p][2], res[p][3]);
}

// ---------------------------------------------------------------------------
extern "C" void kernel_launch(void* const* d_in, const int* in_sizes, int n_in,
                              void* d_out, int out_size, void* d_ws, size_t ws_size,
                              hipStream_t stream) {
    const float* image     = (const float*)d_in[0];  // (3,2048,2048)
    const float* mask      = (const float*)d_in[1];  // (1,2048,2048)
    const float* drand     = (const float*)d_in[2];  // (1,2,2048,2048)
    const float* log_sigma = (const float*)d_in[3];  // (2,)
    const float* log_alpha = (const float*)d_in[4];  // (2,)
    float* out = (float*)d_out;                      // 3*HW img ++ 1*HW mask

    const size_t HW = (size_t)H * W;
    const bool can_pack = ws_size >= (6 * HW + 256) * sizeof(float);

    float4* packed; float* tmp; float* wts;
    if (can_pack) {
        packed = (float4*)d_ws;                  // 4*HW floats (64 MB), 16B aligned
        tmp    = (float*)d_ws + 4 * HW;          // 2*HW floats (32 MB)
        wts    = tmp + 2 * HW;                   // 226 floats
    } else {
        packed = nullptr;
        tmp    = (float*)d_ws;
        wts    = tmp + 2 * HW;
    }

    make_weights_k<<<1, 128, 0, stream>>>(log_sigma, log_alpha, wts);
    if (can_pack)
        pack_k<<<(int)(HW / 256), 256, 0, stream>>>(image, mask, packed);
    vblur_k<<<dim3(W / 512, H / TR, 2), 256, 0, stream>>>(drand, wts, tmp);
    if (can_pack)
        hblur_sample_k<true><<<H, 512, 0, stream>>>(tmp, wts, image, mask, packed, out);
    else
        hblur_sample_k<false><<<H, 512, 0, stream>>>(tmp, wts, image, mask, packed, out);
}

// Round 5
// 246.077 us; speedup vs baseline: 3.3869x; 1.0806x over previous
//
#include <hip/hip_runtime.h>

#define H 2048
#define W 2048
#define KS 97      // int(2*(4*12+0.5)) = 97, odd
#define KH 48
#define KPAD 112   // taps zero-padded to multiple of 16; g[97..111] = 0
#define TR 16      // output rows per thread, vertical pass (== ring depth == unroll)
#define NB_VB 1024 // vblur blocks: (2048/512) x (2048/16) x 2
#define NB_PK 4096 // pack blocks: HW/(256*4)

// ---------------------------------------------------------------------------
// wts layout: [0..111]=g0 (sigma0, zero-padded), [112..223]=g1, [224]=a0, [225]=a1
// ---------------------------------------------------------------------------
__global__ __launch_bounds__(128) void make_weights_k(const float* __restrict__ log_sigma,
                                                      const float* __restrict__ log_alpha,
                                                      float* __restrict__ wts) {
    __shared__ float e0s[KS], e1s[KS];
    __shared__ float sums[2];
    const int t = threadIdx.x;
    const float s0 = expf(log_sigma[0]);
    const float s1 = expf(log_sigma[1]);
    if (t < KS) {
        const float xx = (float)(t - KH);
        e0s[t] = expf(-(xx * xx) / (2.f * s0 * s0));
        e1s[t] = expf(-(xx * xx) / (2.f * s1 * s1));
    }
    __syncthreads();
    if (t == 0) {
        float a = 0.f, b = 0.f;
        for (int k = 0; k < KS; ++k) { a += e0s[k]; b += e1s[k]; }
        sums[0] = a; sums[1] = b;
    }
    __syncthreads();
    if (t < KPAD) {
        wts[t]        = (t < KS) ? e0s[t] / sums[0] : 0.f;
        wts[KPAD + t] = (t < KS) ? e1s[t] / sums[1] : 0.f;
    }
    if (t == 0) {
        wts[2 * KPAD]     = expf(log_alpha[0]);
        wts[2 * KPAD + 1] = expf(log_alpha[1]);
    }
}

// ---------------------------------------------------------------------------
// Vertical-blur body: 16 output rows/thread, 2 cols (float2), 16-deep ring.
// CRITICAL: inner r-loop fully unrolled so (r+t)&15 is compile-time constant
// -> registers, never scratch (R3's spill bug).
// ---------------------------------------------------------------------------
template <bool GUARD>
__device__ __forceinline__ float2 vload_row(const float* __restrict__ src, int row, int col) {
    float2 v = make_float2(0.f, 0.f);
    if (!GUARD || ((unsigned)row < (unsigned)H)) {
        const float2 r2 = *(const float2*)(src + (size_t)row * W + col);
        v.x = fmaf(r2.x, 2.f, -1.f);
        v.y = fmaf(r2.y, 2.f, -1.f);
    }
    return v;
}

template <bool GUARD>
__device__ __forceinline__ void vblur_body(const float* __restrict__ src,
                                           const float* __restrict__ g,
                                           float* __restrict__ dst,
                                           int col, int i0) {
    const int base = i0 - KH;
    float2 win[16];
    float2 acc[TR];
#pragma unroll
    for (int t = 0; t < TR; ++t) acc[t] = make_float2(0.f, 0.f);
#pragma unroll
    for (int t = 0; t < 15; ++t) win[t] = vload_row<GUARD>(src, base + t, col);

    for (int m = 0; m < KPAD / 16; ++m) {       // 7 groups, dynamic loop
        const int kb = m * 16;
#pragma unroll
        for (int r = 0; r < 16; ++r) {          // fully unrolled: static ring idx
            const int k = kb + r;
            win[(r + 15) & 15] = vload_row<GUARD>(src, base + k + 15, col);
            const float gk = g[k];              // uniform -> s_load; 0 for k>=97
#pragma unroll
            for (int t = 0; t < TR; ++t) {
                const float2 u = win[(r + t) & 15];
                acc[t].x = fmaf(gk, u.x, acc[t].x);
                acc[t].y = fmaf(gk, u.y, acc[t].y);
            }
        }
    }
#pragma unroll
    for (int t = 0; t < TR; ++t)
        *(float2*)(dst + (size_t)(i0 + t) * W + col) = acc[t];
}

// ---------------------------------------------------------------------------
// Fused kernel: blocks [0,1024) do vertical blur (XCD y-band swizzle),
// blocks [1024, 5120) pack image+mask into interleaved float4 (4 px/thread).
// The two jobs are data-independent; fusing them makes the GPU overlap the
// VALU/L2-bound blur with the pure-HBM pack instead of serializing launches.
// ---------------------------------------------------------------------------
__global__ __launch_bounds__(256, 4) void pv_k(const float* __restrict__ drand,
                                               const float* __restrict__ wts,
                                               const float* __restrict__ image,
                                               const float* __restrict__ mask,
                                               float* __restrict__ tmp,
                                               float4* __restrict__ packed) {
    const size_t HW = (size_t)H * W;
    const int bid = blockIdx.x;
    if (bid < NB_VB) {
        // --- vertical blur ---
        const int c   = bid >> 9;          // 512 blocks per channel
        const int id  = bid & 511;
        const int xcd = id & 7;            // XCD-band swizzle: each XCD gets a
        const int seq = id >> 3;           // contiguous 16-yblock (256-row) band
        const int yb  = xcd * 16 + (seq >> 2);
        const int xb  = seq & 3;
        const int col = (xb * 256 + threadIdx.x) * 2;
        const int i0  = yb * TR;
        const float* __restrict__ src = drand + (size_t)c * HW;
        const float* __restrict__ g   = wts + c * KPAD;
        float* __restrict__ dst       = tmp + (size_t)c * HW;
        // rows touched: [i0-48, i0+78]
        if (i0 >= KH && i0 + 78 <= H - 1)
            vblur_body<false>(src, g, dst, col, i0);
        else
            vblur_body<true>(src, g, dst, col, i0);
    } else {
        // --- pack: 4 px/thread, all loads/stores dwordx4 ---
        const size_t idx4 = ((size_t)(bid - NB_VB) * 256 + threadIdx.x) * 4;
        const float4 p0 = *(const float4*)(image + idx4);
        const float4 p1 = *(const float4*)(image + HW + idx4);
        const float4 p2 = *(const float4*)(image + 2 * HW + idx4);
        const float4 pm = *(const float4*)(mask + idx4);
        packed[idx4 + 0] = make_float4(p0.x, p1.x, p2.x, pm.x);
        packed[idx4 + 1] = make_float4(p0.y, p1.y, p2.y, pm.y);
        packed[idx4 + 2] = make_float4(p0.z, p1.z, p2.z, pm.z);
        packed[idx4 + 3] = make_float4(p0.w, p1.w, p2.w, pm.w);
    }
}

// ---------------------------------------------------------------------------
// Kernel 2: one block per row (512 thr x 4 px), XCD row-band swizzle.
// Horizontal 97-tap blur of tmp -> (dy,dx), scale by alpha, bilinear gather,
// write 4 planes. PACKED: corners via one dwordx4 from interleaved buffer.
// Reference quirk: x-coordinate += dy (channel 0), y-coordinate += dx.
// ---------------------------------------------------------------------------
#define SW 2160     // LDS span: need idx <= 2155; mult of 4
template <bool PACKED>
__global__ __launch_bounds__(512) void hblur_sample_k(const float* __restrict__ tmp,
                                                      const float* __restrict__ wts,
                                                      const float* __restrict__ image,
                                                      const float* __restrict__ mask,
                                                      const float4* __restrict__ packed,
                                                      float* __restrict__ out) {
    // XCD band swizzle: XCD k walks rows [256k, 256k+256) in order, so the
    // +-40-row gather window stays in that XCD's L2 (holds ~128 packed rows).
    const int i   = (blockIdx.x & 7) * 256 + (blockIdx.x >> 3);
    const int tid = threadIdx.x;

    __shared__ __align__(16) float s0[SW];
    __shared__ __align__(16) float s1[SW];
    __shared__ __align__(16) float g0s[KPAD];
    __shared__ __align__(16) float g1s[KPAD];

    if (tid < KPAD) { g0s[tid] = wts[tid]; g1s[tid] = wts[KPAD + tid]; }

    const float* __restrict__ t0 = tmp + (size_t)i * W;
    const float* __restrict__ t1 = tmp + (size_t)H * W + (size_t)i * W;
    for (int idx = tid; idx < SW / 4; idx += 512) {
        const int colb = idx * 4 - KH;        // 16B aligned; all-in or all-out
        float4 v0 = make_float4(0.f, 0.f, 0.f, 0.f);
        float4 v1 = v0;
        if (colb >= 0 && colb + 3 < W) {
            v0 = *(const float4*)(t0 + colb);
            v1 = *(const float4*)(t1 + colb);
        }
        *(float4*)(s0 + idx * 4) = v0;
        *(float4*)(s1 + idx * 4) = v1;
    }
    __syncthreads();

    const int lb = tid * 4;                   // first of 4 pixels

    float4 A0 = *(const float4*)(s0 + lb), B0 = *(const float4*)(s0 + lb + 4);
    float4 A1 = *(const float4*)(s1 + lb), B1 = *(const float4*)(s1 + lb + 4);
    float dy[4] = {0.f, 0.f, 0.f, 0.f}, dx[4] = {0.f, 0.f, 0.f, 0.f};

#pragma unroll
    for (int kg = 0; kg < 26; ++kg) {         // 26 groups of 4 taps (g[97..103]=0)
        const int k0 = kg * 4;
        const float4 g0q = *(const float4*)(g0s + k0);       // broadcast
        const float4 g1q = *(const float4*)(g1s + k0);
        const float4 N0  = *(const float4*)(s0 + lb + k0 + 8);
        const float4 N1  = *(const float4*)(s1 + lb + k0 + 8);
        const float e0[8] = {A0.x, A0.y, A0.z, A0.w, B0.x, B0.y, B0.z, B0.w};
        const float e1[8] = {A1.x, A1.y, A1.z, A1.w, B1.x, B1.y, B1.z, B1.w};
#pragma unroll
        for (int j = 0; j < 4; ++j) {
            const float gj0 = j == 0 ? g0q.x : j == 1 ? g0q.y : j == 2 ? g0q.z : g0q.w;
            const float gj1 = j == 0 ? g1q.x : j == 1 ? g1q.y : j == 2 ? g1q.z : g1q.w;
#pragma unroll
            for (int c = 0; c < 4; ++c) {
                dy[c] = fmaf(gj0, e0[c + j], dy[c]);
                dx[c] = fmaf(gj1, e1[c + j], dx[c]);
            }
        }
        A0 = B0; B0 = N0; A1 = B1; B1 = N1;
    }

    const float a0 = wts[2 * KPAD];
    const float a1 = wts[2 * KPAD + 1];
    const float step = 2.f / 2047.f;
    float res[4][4];
#pragma unroll
    for (int c = 0; c < 4; ++c) {
        const int j = lb + c;
        const float dyc = dy[c] * a0;
        const float dxc = dx[c] * a1;
        float xn = -1.f + (float)j * step + dyc;   // gx + dy  (reference quirk)
        float yn = -1.f + (float)i * step + dxc;   // gy + dx
        xn = fminf(fmaxf(xn, -1.f), 1.f);
        yn = fminf(fmaxf(yn, -1.f), 1.f);

        const float x = (xn + 1.f) * 0.5f * (float)(W - 1);
        const float y = (yn + 1.f) * 0.5f * (float)(H - 1);
        const float x0f = floorf(x), y0f = floorf(y);
        const float wx = x - x0f, wy = y - y0f;

        int x0 = (int)x0f, y0 = (int)y0f;
        int x1 = x0 + 1, y1 = y0 + 1;
        x0 = min(max(x0, 0), W - 1); x1 = min(max(x1, 0), W - 1);
        y0 = min(max(y0, 0), H - 1); y1 = min(max(y1, 0), H - 1);

        const float w00 = (1.f - wx) * (1.f - wy);
        const float w10 = wx * (1.f - wy);
        const float w01 = (1.f - wx) * wy;
        const float w11 = wx * wy;

        const size_t i00 = (size_t)y0 * W + x0;
        const size_t i10 = (size_t)y0 * W + x1;
        const size_t i01 = (size_t)y1 * W + x0;
        const size_t i11 = (size_t)y1 * W + x1;

        if (PACKED) {
            const float4 v00 = packed[i00], v10 = packed[i10];
            const float4 v01 = packed[i01], v11 = packed[i11];
            res[0][c] = v00.x * w00 + v10.x * w10 + v01.x * w01 + v11.x * w11;
            res[1][c] = v00.y * w00 + v10.y * w10 + v01.y * w01 + v11.y * w11;
            res[2][c] = v00.z * w00 + v10.z * w10 + v01.z * w01 + v11.z * w11;
            res[3][c] = v00.w * w00 + v10.w * w10 + v01.w * w01 + v11.w * w11;
        } else {
#pragma unroll
            for (int p = 0; p < 3; ++p) {
                const float* __restrict__ pl = image + (size_t)p * H * W;
                res[p][c] = pl[i00] * w00 + pl[i10] * w10 + pl[i01] * w01 + pl[i11] * w11;
            }
            res[3][c] = mask[i00] * w00 + mask[i10] * w10 + mask[i01] * w01 + mask[i11] * w11;
        }
    }

    const size_t o = (size_t)i * W + lb;
#pragma unroll
    for (int p = 0; p < 4; ++p)
        *(float4*)(out + (size_t)p * H * W + o) =
            make_float4(res[p][0], res[p][1], res[p][2], res[p][3]);
}

// ---------------------------------------------------------------------------
extern "C" void kernel_launch(void* const* d_in, const int* in_sizes, int n_in,
                              void* d_out, int out_size, void* d_ws, size_t ws_size,
                              hipStream_t stream) {
    const float* image     = (const float*)d_in[0];  // (3,2048,2048)
    const float* mask      = (const float*)d_in[1];  // (1,2048,2048)
    const float* drand     = (const float*)d_in[2];  // (1,2,2048,2048)
    const float* log_sigma = (const float*)d_in[3];  // (2,)
    const float* log_alpha = (const float*)d_in[4];  // (2,)
    float* out = (float*)d_out;                      // 3*HW img ++ 1*HW mask

    const size_t HW = (size_t)H * W;
    const bool can_pack = ws_size >= (6 * HW + 256) * sizeof(float);

    float4* packed; float* tmp; float* wts;
    if (can_pack) {
        packed = (float4*)d_ws;                  // 4*HW floats (64 MB), 16B aligned
        tmp    = (float*)d_ws + 4 * HW;          // 2*HW floats (32 MB)
        wts    = tmp + 2 * HW;                   // 226 floats
    } else {
        packed = nullptr;
        tmp    = (float*)d_ws;
        wts    = tmp + 2 * HW;
    }

    make_weights_k<<<1, 128, 0, stream>>>(log_sigma, log_alpha, wts);
    pv_k<<<can_pack ? (NB_VB + NB_PK) : NB_VB, 256, 0, stream>>>(drand, wts, image, mask,
                                                                 tmp, packed);
    if (can_pack)
        hblur_sample_k<true><<<H, 512, 0, stream>>>(tmp, wts, image, mask, packed, out);
    else
        hblur_sample_k<false><<<H, 512, 0, stream>>>(tmp, wts, image, mask, packed, out);
}